// Round 9
// baseline (454.891 us; speedup 1.0000x reference)
//
#include <hip/hip_runtime.h>

#define NROWS 16384
#define KCODES 8192
#define DDIM 256
#define MARGIN 2.0f
#define SEG 256
#define NCI 8    // col-tiles swept per block
#define GATHER_BLOCKS (NROWS / 16)

typedef __attribute__((ext_vector_type(8))) short short8;
typedef __attribute__((ext_vector_type(4))) float f32x4;

// ---------------- helpers ----------------
__device__ inline unsigned short f2bf(float x) {
    unsigned u = __float_as_uint(x);
    return (unsigned short)((u + 0x7FFFu + ((u >> 16) & 1u)) >> 16);  // RNE
}

__device__ inline void gload16(const void* g, void* l) {
    __builtin_amdgcn_global_load_lds(
        (const __attribute__((address_space(1))) unsigned char*)g,
        (__attribute__((address_space(3))) unsigned char*)l, 16, 0, 0);
}

__device__ inline unsigned mbcnt64(unsigned long long m) {
    unsigned lo = __builtin_amdgcn_mbcnt_lo((unsigned)m, 0u);
    return __builtin_amdgcn_mbcnt_hi((unsigned)(m >> 32), lo);
}

__device__ inline void exact_rescore(const float* __restrict__ z, const float* __restrict__ cb,
                                     const float* __restrict__ z2g, const float* __restrict__ e2g,
                                     int grow, int gcol, unsigned long long* best) {
    const float4* av = reinterpret_cast<const float4*>(z + (size_t)grow * DDIM);
    const float4* bv = reinterpret_cast<const float4*>(cb + (size_t)gcol * DDIM);
    float dot = 0.f;
    #pragma unroll 8
    for (int j = 0; j < 64; ++j) {
        const float4 xa = av[j], xb = bv[j];
        dot = fmaf(xa.x, xb.x, fmaf(xa.y, xb.y, fmaf(xa.z, xb.z, fmaf(xa.w, xb.w, dot))));
    }
    const float de = z2g[grow] + e2g[gcol] - 2.0f * dot;
    const unsigned long long key =
        ((unsigned long long)__float_as_uint(de) << 32) | (unsigned)gcol;
    atomicMin(best + grow, key);
}

// ---------------- convert fp32 -> bf16 pre-tiled fragment layout + fused sumsq ----------------
// chunk (g, kb2): 1 KB, slot s: row g*16 + (s&15), k = kb2*32 + (s>>4)*8 .. +8
__global__ __launch_bounds__(256) void k_convert(
    const float* __restrict__ z, unsigned short* __restrict__ z_t,
    const float* __restrict__ cb, unsigned short* __restrict__ cb_t,
    float* __restrict__ z2, float* __restrict__ e2,
    unsigned long long* best, unsigned* amin, float* accum, unsigned* counter, unsigned* gctr)
{
    const int tid = threadIdx.x;
    const int bx = blockIdx.x;
    if (bx < 64) {
        const int gid = bx * 256 + tid;
        best[gid] = 0xFFFFFFFFFFFFFFFFull;
        amin[gid] = 0x7F800000u;
        if (gid == 0) { accum[0] = 0.0f; counter[0] = 0u; gctr[0] = 0u; }
    }
    const float* in;
    unsigned short* outt;
    float* sumsq;
    int g;
    if (bx < 256) { in = z;  outt = z_t;  sumsq = z2; g = bx * 4 + (tid >> 6); }
    else          { in = cb; outt = cb_t; sumsq = e2; g = (bx - 256) * 4 + (tid >> 6); }
    const int lane = tid & 63;
    const int row = g * 16 + (lane & 15);
    const int ko = (lane >> 4) * 8;
    float ss = 0.f;
    #pragma unroll
    for (int kb2 = 0; kb2 < 8; ++kb2) {
        const float4* src = reinterpret_cast<const float4*>(in + (size_t)row * DDIM + kb2 * 32 + ko);
        const float4 a = src[0], b = src[1];
        ss += a.x * a.x + a.y * a.y + a.z * a.z + a.w * a.w
            + b.x * b.x + b.y * b.y + b.z * b.z + b.w * b.w;
        short8 p;
        p[0] = (short)f2bf(a.x); p[1] = (short)f2bf(a.y); p[2] = (short)f2bf(a.z); p[3] = (short)f2bf(a.w);
        p[4] = (short)f2bf(b.x); p[5] = (short)f2bf(b.y); p[6] = (short)f2bf(b.z); p[7] = (short)f2bf(b.w);
        *reinterpret_cast<short8*>(outt + (((size_t)(g * 8 + kb2)) << 9) + lane * 8) = p;
    }
    ss += __shfl_xor(ss, 16);
    ss += __shfl_xor(ss, 32);
    if (lane < 16) sumsq[g * 16 + lane] = ss;
}

// ---------------- MFMA screen: A-band resident, barrier-free per-wave sweep ----------------
// LDS: A[0,65536) 64 chunks | wave lists 8*SEG u32 | z2lds[128] | aminlds[128]
__global__ __launch_bounds__(512, 2) void k_screen(
    const float* __restrict__ z, const float* __restrict__ cbp,
    const unsigned short* __restrict__ z_t, const unsigned short* __restrict__ cb_t,
    const float* __restrict__ z2g, const float* __restrict__ e2g,
    unsigned* amin, unsigned long long* best,
    unsigned* counter, unsigned* list, unsigned C)
{
    __shared__ __align__(16) char smem[65536 + 8 * SEG * 4 + 1024];
    char* ldsA = smem;
    unsigned* wl_all = (unsigned*)(smem + 65536);
    float* z2lds = (float*)(smem + 65536 + 8 * SEG * 4);
    unsigned* aminlds = (unsigned*)(smem + 65536 + 8 * SEG * 4 + 512);

    const int tid = threadIdx.x;
    const int lane = tid & 63;
    const int wave = tid >> 6;     // 0..7
    const int wm = wave & 1;       // 64-row half
    const int wn = wave >> 1;      // 64-col quarter
    const int lhi = lane >> 4;
    const int llo = lane & 15;

    const int bx = blockIdx.x;     // 512 blocks
    const int rt = bx & 127;       // row band (128 rows)
    const int cgrp = bx >> 7;      // 0..3
    const int row0 = rt * 128;

    // prologue: stage A band (64 KB) + z2/amin mirrors, one barrier
    #pragma unroll
    for (int i = 0; i < 8; ++i) {
        const int c = wave * 8 + i;                 // gl = c>>3, kb2 = c&7
        gload16((const char*)z_t + (((size_t)((rt * 8 + (c >> 3)) * 8 + (c & 7))) << 10) + lane * 16,
                ldsA + c * 1024);
    }
    if (tid < 128) { z2lds[tid] = z2g[row0 + tid]; aminlds[tid] = amin[row0 + tid]; }
    __syncthreads();   // A band + mirrors ready (vmcnt drained)

    unsigned* wl = wl_all + wave * SEG;
    f32x4 rm[4];
    #pragma unroll
    for (int i = 0; i < 4; ++i) { rm[i][0] = 3.0e38f; rm[i][1] = 3.0e38f; rm[i][2] = 3.0e38f; rm[i][3] = 3.0e38f; }

    #pragma unroll 1
    for (int ci = 0; ci < NCI; ++ci) {
        const int ct = cgrp * NCI + ci;
        const int col0 = ct * 256;

        // racy refresh of the amin mirror (any stale value is conservative)
        if (tid < 128) aminlds[tid] = amin[row0 + tid];

        f32x4 acc[4][4];
        const f32x4 zero = {0.f, 0.f, 0.f, 0.f};
        #pragma unroll
        for (int i = 0; i < 4; ++i)
            #pragma unroll
            for (int j = 0; j < 4; ++j) acc[i][j] = zero;

        // barrier-free K-loop: B fragments straight from global (L2/L3) to registers
        const char* bbase = (const char*)cb_t + (size_t)ct * 131072 + (size_t)wn * 32768 + (size_t)lane * 16;
        const char* abase = ldsA + wm * 32768 + lane * 16;
        #pragma unroll 2
        for (int ks = 0; ks < 4; ++ks) {
            #pragma unroll
            for (int kk = 0; kk < 2; ++kk) {
                short8 bfr[4];
                #pragma unroll
                for (int fn = 0; fn < 4; ++fn)
                    bfr[fn] = *reinterpret_cast<const short8*>(bbase + fn * 8192 + ks * 2048 + kk * 1024);
                #pragma unroll
                for (int fm = 0; fm < 4; ++fm) {
                    const short8 af = *reinterpret_cast<const short8*>(abase + fm * 8192 + ks * 2048 + kk * 1024);
                    #pragma unroll
                    for (int fn = 0; fn < 4; ++fn)
                        acc[fm][fn] = __builtin_amdgcn_mfma_f32_16x16x32_bf16(af, bfr[fn], acc[fm][fn], 0, 0, 0);
                }
            }
        }

        // ---- barrier-free per-wave epilogue ----
        const int cbase = col0 + wn * 64;
        float e2c[4];
        #pragma unroll
        for (int fn = 0; fn < 4; ++fn) e2c[fn] = e2g[cbase + fn * 16 + llo];

        unsigned wcount = 0;
        #pragma unroll
        for (int fm = 0; fm < 4; ++fm) {
            #pragma unroll
            for (int rg = 0; rg < 4; ++rg) {
                const int rl = wm * 64 + fm * 16 + lhi * 4 + rg;
                const int grow = row0 + rl;
                const float z2v = z2lds[rl];
                float d[4];
                #pragma unroll
                for (int fn = 0; fn < 4; ++fn) d[fn] = z2v + e2c[fn] - 2.0f * acc[fm][fn][rg];
                float m = fminf(fminf(d[0], d[1]), fminf(d[2], d[3]));
                #pragma unroll
                for (int off = 1; off < 16; off <<= 1) m = fminf(m, __shfl_xor(m, off));
                const float rmv = fminf(rm[fm][rg], m);
                rm[fm][rg] = rmv;
                const float aminv = __uint_as_float(aminlds[rl]);
                if (llo == 0 && rmv < aminv)
                    atomicMin(&amin[grow], __float_as_uint(rmv));   // fire-and-forget hint
                const float thr = fminf(rmv, aminv) + MARGIN;
                #pragma unroll
                for (int fn = 0; fn < 4; ++fn) {
                    const bool p = d[fn] <= thr;
                    const unsigned long long mask = __ballot(p);
                    if (mask) {
                        if (p) {
                            const unsigned pos = wcount + mbcnt64(mask);
                            const unsigned v = ((unsigned)grow << 13) | (unsigned)(cbase + fn * 16 + llo);
                            if (pos < SEG) wl[pos] = v;
                            else exact_rescore(z, cbp, z2g, e2g, grow, cbase + fn * 16 + llo, best);
                        }
                        wcount += (unsigned)__popcll(mask);
                    }
                }
            }
        }

        // per-wave flush: one global atomicAdd, coalesced copy
        const unsigned n = wcount < SEG ? wcount : SEG;
        unsigned base = 0;
        if (lane == 0 && n) base = atomicAdd(counter, n);
        base = (unsigned)__shfl((int)base, 0);
        for (unsigned i = lane; i < n; i += 64) {
            const unsigned v = wl[i];
            const unsigned slot = base + i;
            if (slot < C) list[slot] = v;
            else exact_rescore(z, cbp, z2g, e2g, (int)(v >> 13), (int)(v & 8191u), best);
        }
    }
}

// ---------------- exact rescore of candidate list (wave per candidate) ----------------
__global__ __launch_bounds__(256) void k_rescore(
    const float* __restrict__ z, const float* __restrict__ cbp,
    const float* __restrict__ z2g, const float* __restrict__ e2g,
    const unsigned* __restrict__ list, const unsigned* __restrict__ counter, unsigned C,
    unsigned long long* best)
{
    const unsigned n = min(counter[0], C);
    const unsigned wid = (blockIdx.x * blockDim.x + threadIdx.x) >> 6;
    const unsigned nw = (gridDim.x * blockDim.x) >> 6;
    const int lane = threadIdx.x & 63;
    for (unsigned i = wid; i < n; i += nw) {
        const unsigned v = list[i];
        const unsigned row = v >> 13, col = v & 8191u;
        const float4 a = *reinterpret_cast<const float4*>(z + (size_t)row * DDIM + lane * 4);
        const float4 b = *reinterpret_cast<const float4*>(cbp + (size_t)col * DDIM + lane * 4);
        float s = fmaf(a.x, b.x, fmaf(a.y, b.y, fmaf(a.z, b.z, a.w * b.w)));
        #pragma unroll
        for (int off = 1; off < 64; off <<= 1) s += __shfl_xor(s, off);
        if (lane == 0) {
            const float de = z2g[row] + e2g[col] - 2.0f * s;
            const unsigned long long key =
                ((unsigned long long)__float_as_uint(de) << 32) | col;
            atomicMin(&best[row], key);
        }
    }
}

// ---------------- gather + z_st + loss + final scalars (ticket) ----------------
__global__ __launch_bounds__(1024) void k_gather(
    const float* __restrict__ z, const float* __restrict__ cbp,
    const unsigned long long* __restrict__ best,
    float* __restrict__ out, float* __restrict__ accum, unsigned* __restrict__ gctr)
{
    __shared__ float wsum[16];
    const int tid = threadIdx.x;
    const int row = blockIdx.x * 16 + (tid >> 6);
    const int lane = tid & 63;
    const unsigned k = (unsigned)(best[row] & 0xFFFFFFFFull);
    const float4 ze = *reinterpret_cast<const float4*>(z + (size_t)row * DDIM + lane * 4);
    const float4 cq = *reinterpret_cast<const float4*>(cbp + (size_t)k * DDIM + lane * 4);
    float4 zst;
    zst.x = ze.x + (cq.x - ze.x); zst.y = ze.y + (cq.y - ze.y);
    zst.z = ze.z + (cq.z - ze.z); zst.w = ze.w + (cq.w - ze.w);
    *reinterpret_cast<float4*>(out + (size_t)row * DDIM + lane * 4) = zst;
    const float dx = cq.x - ze.x, dy = cq.y - ze.y, dz = cq.z - ze.z, dw = cq.w - ze.w;
    float s = dx * dx + dy * dy + dz * dz + dw * dw;
    #pragma unroll
    for (int off = 32; off > 0; off >>= 1) s += __shfl_down(s, off);
    if (lane == 0) {
        wsum[tid >> 6] = s;
        out[(size_t)NROWS * DDIM + row] = (float)k;
    }
    __syncthreads();
    if (tid == 0) {
        float tot = 0.f;
        #pragma unroll
        for (int i = 0; i < 16; ++i) tot += wsum[i];
        atomicAdd(accum, tot);
        __threadfence();
        const unsigned t = atomicAdd(gctr, 1u);
        if (t == GATHER_BLOCKS - 1) {   // last block: all accum adds complete
            const float total = atomicAdd(accum, 0.0f);
            const float m = total / (float)(NROWS * DDIM);
            out[(size_t)NROWS * DDIM + NROWS + 0] = m;
            out[(size_t)NROWS * DDIM + NROWS + 1] = m;
        }
    }
}

extern "C" void kernel_launch(void* const* d_in, const int* in_sizes, int n_in,
                              void* d_out, int out_size, void* d_ws, size_t ws_size,
                              hipStream_t stream)
{
    const float* z  = (const float*)d_in[0];
    const float* cb = (const float*)d_in[1];
    float* out = (float*)d_out;

    // bf16 pre-tiled scratch lives in d_out's z_st region (12 MB of 16.8 MB),
    // consumed by k_screen and fully overwritten afterwards by k_gather.
    unsigned short* z_t  = (unsigned short*)d_out;                      // 8 MB
    unsigned short* cb_t = (unsigned short*)((char*)d_out + 8388608);   // 4 MB

    char* ws = (char*)d_ws;
    unsigned long long* best = (unsigned long long*)ws;            // 131072 B
    unsigned* amin = (unsigned*)(ws + 131072);                     // 65536 B
    float* e2    = (float*)(ws + 131072 + 65536);                  // 32768 B
    float* z2    = (float*)(ws + 131072 + 65536 + 32768);          // 65536 B
    float* accum   = (float*)(ws + 294912);
    unsigned* counter = (unsigned*)(ws + 294916);
    unsigned* gctr  = (unsigned*)(ws + 294920);
    unsigned* list = (unsigned*)(ws + 295936);
    unsigned C = 0;
    if (ws_size > 295936 + 16) {
        size_t c = (ws_size - 295936) / 4;
        if (c > 4194304) c = 4194304;
        C = (unsigned)c;
    }

    k_convert<<<384, 256, 0, stream>>>(z, z_t, cb, cb_t, z2, e2, best, amin, accum, counter, gctr);
    k_screen<<<512, 512, 0, stream>>>(z, cb, z_t, cb_t, z2, e2, amin, best, counter, list, C);
    k_rescore<<<2048, 256, 0, stream>>>(z, cb, z2, e2, list, counter, C, best);
    k_gather<<<GATHER_BLOCKS, 1024, 0, stream>>>(z, cb, best, out, accum, gctr);
}

// Round 10
// 397.290 us; speedup vs baseline: 1.1450x; 1.1450x over previous
//
#include <hip/hip_runtime.h>

#define NROWS 16384
#define KCODES 8192
#define DDIM 256
#define MARGIN 2.0f
#define SEG 256
#define NCI 8     // 512-col tiles per block (block sweeps 4096 cols)
#define GATHER_BLOCKS (NROWS / 16)

typedef __attribute__((ext_vector_type(8))) short short8;
typedef __attribute__((ext_vector_type(4))) float f32x4;

// ---------------- helpers ----------------
__device__ inline unsigned short f2bf(float x) {
    unsigned u = __float_as_uint(x);
    return (unsigned short)((u + 0x7FFFu + ((u >> 16) & 1u)) >> 16);  // RNE
}

__device__ inline void gload16(const void* g, void* l) {
    __builtin_amdgcn_global_load_lds(
        (const __attribute__((address_space(1))) unsigned char*)g,
        (__attribute__((address_space(3))) unsigned char*)l, 16, 0, 0);
}

__device__ inline unsigned mbcnt64(unsigned long long m) {
    unsigned lo = __builtin_amdgcn_mbcnt_lo((unsigned)m, 0u);
    return __builtin_amdgcn_mbcnt_hi((unsigned)(m >> 32), lo);
}

__device__ inline void exact_rescore(const float* __restrict__ z, const float* __restrict__ cb,
                                     const float* __restrict__ z2g, const float* __restrict__ e2g,
                                     int grow, int gcol, unsigned long long* best) {
    const float4* av = reinterpret_cast<const float4*>(z + (size_t)grow * DDIM);
    const float4* bv = reinterpret_cast<const float4*>(cb + (size_t)gcol * DDIM);
    float dot = 0.f;
    #pragma unroll 8
    for (int j = 0; j < 64; ++j) {
        const float4 xa = av[j], xb = bv[j];
        dot = fmaf(xa.x, xb.x, fmaf(xa.y, xb.y, fmaf(xa.z, xb.z, fmaf(xa.w, xb.w, dot))));
    }
    const float de = z2g[grow] + e2g[gcol] - 2.0f * dot;
    const unsigned long long key =
        ((unsigned long long)__float_as_uint(de) << 32) | (unsigned)gcol;
    atomicMin(best + grow, key);
}

// ---------------- convert fp32 -> bf16 pre-tiled fragment layout + fused sumsq ----------------
// chunk (g, kb2): 1 KB, slot s: row g*16 + (s&15), k = kb2*32 + (s>>4)*8 .. +8
__global__ __launch_bounds__(256) void k_convert(
    const float* __restrict__ z, unsigned short* __restrict__ z_t,
    const float* __restrict__ cb, unsigned short* __restrict__ cb_t,
    float* __restrict__ z2, float* __restrict__ e2,
    unsigned long long* best, float* accum, unsigned* counters, unsigned* gctr)
{
    const int tid = threadIdx.x;
    const int bx = blockIdx.x;
    if (bx < 64) {
        const int gid = bx * 256 + tid;
        best[gid] = 0xFFFFFFFFFFFFFFFFull;
    }
    if (bx == 0) {
        if (tid < 8) counters[tid * 16] = 0u;
        if (tid == 0) { accum[0] = 0.0f; gctr[0] = 0u; }
    }
    const float* in;
    unsigned short* outt;
    float* sumsq;
    int g;
    if (bx < 256) { in = z;  outt = z_t;  sumsq = z2; g = bx * 4 + (tid >> 6); }
    else          { in = cb; outt = cb_t; sumsq = e2; g = (bx - 256) * 4 + (tid >> 6); }
    const int lane = tid & 63;
    const int row = g * 16 + (lane & 15);
    const int ko = (lane >> 4) * 8;
    float ss = 0.f;
    #pragma unroll
    for (int kb2 = 0; kb2 < 8; ++kb2) {
        const float4* src = reinterpret_cast<const float4*>(in + (size_t)row * DDIM + kb2 * 32 + ko);
        const float4 a = src[0], b = src[1];
        ss += a.x * a.x + a.y * a.y + a.z * a.z + a.w * a.w
            + b.x * b.x + b.y * b.y + b.z * b.z + b.w * b.w;
        short8 p;
        p[0] = (short)f2bf(a.x); p[1] = (short)f2bf(a.y); p[2] = (short)f2bf(a.z); p[3] = (short)f2bf(a.w);
        p[4] = (short)f2bf(b.x); p[5] = (short)f2bf(b.y); p[6] = (short)f2bf(b.z); p[7] = (short)f2bf(b.w);
        *reinterpret_cast<short8*>(outt + (((size_t)(g * 8 + kb2)) << 9) + lane * 8) = p;
    }
    ss += __shfl_xor(ss, 16);
    ss += __shfl_xor(ss, 32);
    if (lane < 16) sumsq[g * 16 + lane] = ss;
}

// ---------------- MFMA screen: A resident, BK=32 dbuf B, barrier-free epilogue ----------------
// LDS: A[0,64K) | B dbuf 2x32K @64K | rowmin[4][128] @131072 | thrbuf[128] @133120
//      z2lds[128] @133632 | aminlds[128] @134144 | wl 8xSEG @134656
__global__ __launch_bounds__(512, 2) void k_screen(
    const float* __restrict__ z, const float* __restrict__ cbp,
    const unsigned short* __restrict__ z_t, const unsigned short* __restrict__ cb_t,
    const float* __restrict__ z2g, const float* __restrict__ e2g,
    unsigned long long* __restrict__ best,
    unsigned* __restrict__ counters, unsigned* __restrict__ list, unsigned C8)
{
    __shared__ __align__(16) char smem[142848];
    char* ldsA = smem;
    char* ldsB = smem + 65536;
    float* rowmin = (float*)(smem + 131072);      // [4][128]
    float* thrbuf = (float*)(smem + 133120);      // [128]
    float* z2lds  = (float*)(smem + 133632);      // [128]
    float* aminlds= (float*)(smem + 134144);      // [128]
    unsigned* wl_all = (unsigned*)(smem + 134656);

    const int tid = threadIdx.x;
    const int lane = tid & 63;
    const int wave = tid >> 6;     // 0..7
    const int wm = wave & 1;       // 64-row half
    const int wn = wave >> 1;      // 64-col quarter (within each 256-subtile)
    const int lhi = lane >> 4;
    const int llo = lane & 15;

    const int bx = blockIdx.x;     // 256 blocks = 128 rt x 2 cgrp
    const int rt = bx & 127;
    const int cgrp = bx >> 7;
    const int row0 = rt * 128;

    // ---- prologue: stage A band (64 KB), init scratch, stage first B ----
    #pragma unroll
    for (int i = 0; i < 8; ++i) {
        const int c = wave * 8 + i;   // gl = c>>3 (row-16-group), kb2 = c&7
        gload16((const char*)z_t + (((size_t)((rt * 8 + (c >> 3)) * 8 + (c & 7))) << 10) + lane * 16,
                ldsA + c * 1024);
    }
    if (tid < 128) {
        z2lds[tid] = z2g[row0 + tid];
        aminlds[tid] = 3.0e38f;
        thrbuf[tid] = 3.0e38f;
    }

    auto STAGE_B = [&](int b, int ct_, int kb2_) {
        char* buf = ldsB + b * 32768;
        #pragma unroll
        for (int i = 0; i < 4; ++i) {
            const int gl2 = wave * 4 + i;           // 0..31 local col-16-group
            gload16((const char*)cb_t + (((size_t)((ct_ * 32 + gl2) * 8 + kb2_)) << 10) + lane * 16,
                    buf + gl2 * 1024);
        }
    };

    STAGE_B(0, cgrp * NCI, 0);
    __syncthreads();   // A + first B landed (vmcnt drained at barrier)

    unsigned* wl = wl_all + wave * SEG;
    f32x4 rm[4];
    #pragma unroll
    for (int i = 0; i < 4; ++i) { rm[i][0] = 3.0e38f; rm[i][1] = 3.0e38f; rm[i][2] = 3.0e38f; rm[i][3] = 3.0e38f; }

    f32x4 acc[4][8];

    #pragma unroll 1
    for (int ci = 0; ci < NCI; ++ci) {
        const int ct = cgrp * NCI + ci;

        #pragma unroll
        for (int i = 0; i < 4; ++i)
            #pragma unroll
            for (int j = 0; j < 8; ++j) { acc[i][j][0] = 0.f; acc[i][j][1] = 0.f; acc[i][j][2] = 0.f; acc[i][j][3] = 0.f; }

        // ---- K loop: 8 steps of K=32, 2-phase double buffer, 1 barrier/step ----
        #pragma unroll
        for (int kb2 = 0; kb2 < 8; ++kb2) {
            const int pb = kb2 & 1;
            if (kb2 < 7) STAGE_B(pb ^ 1, ct, kb2 + 1);
            else if (ci < NCI - 1) STAGE_B(pb ^ 1, ct + 1, 0);   // cross-tile prefetch (lands during epilogue)

            // cross-wave threshold merge for previous tile, hidden in this slot (ordered by K barriers)
            if (kb2 == 1 && ci > 0 && tid < 128) {
                const float m2 = fminf(fminf(rowmin[tid], rowmin[128 + tid]),
                                       fminf(rowmin[256 + tid], rowmin[384 + tid]));
                const float a = fminf(aminlds[tid], m2);
                aminlds[tid] = a;
                thrbuf[tid] = a + MARGIN;
            }

            char* bufB = ldsB + pb * 32768;
            short8 bfr[8];
            #pragma unroll
            for (int fn = 0; fn < 8; ++fn) {
                const int gl2 = (fn < 4) ? (wn * 4 + fn) : (16 + wn * 4 + (fn - 4));
                bfr[fn] = *reinterpret_cast<const short8*>(bufB + gl2 * 1024 + lane * 16);
            }
            #pragma unroll
            for (int fm = 0; fm < 4; ++fm) {
                const short8 af = *reinterpret_cast<const short8*>(
                    ldsA + (((wm * 4 + fm) * 8) + kb2) * 1024 + lane * 16);
                #pragma unroll
                for (int fn = 0; fn < 8; ++fn)
                    acc[fm][fn] = __builtin_amdgcn_mfma_f32_16x16x32_bf16(af, bfr[fn], acc[fm][fn], 0, 0, 0);
            }
            __syncthreads();
        }

        // ---- barrier-free epilogue ----
        const int cb0 = ct * 512 + wn * 64 + llo;
        float e2c[8];
        #pragma unroll
        for (int fn = 0; fn < 8; ++fn)
            e2c[fn] = e2g[(fn < 4) ? (cb0 + fn * 16) : (cb0 + 256 + (fn - 4) * 16)];

        unsigned wcount = 0;
        #pragma unroll
        for (int fm = 0; fm < 4; ++fm) {
            #pragma unroll
            for (int rg = 0; rg < 4; ++rg) {
                const int rl = wm * 64 + fm * 16 + lhi * 4 + rg;
                const int grow = row0 + rl;
                const float z2v = z2lds[rl];
                float d[8];
                #pragma unroll
                for (int fn = 0; fn < 8; ++fn) d[fn] = z2v + e2c[fn] - 2.0f * acc[fm][fn][rg];
                float m = d[0];
                #pragma unroll
                for (int fn = 1; fn < 8; ++fn) m = fminf(m, d[fn]);
                #pragma unroll
                for (int off = 1; off < 16; off <<= 1) m = fminf(m, __shfl_xor(m, off));
                const float rmv = fminf(rm[fm][rg], m);
                rm[fm][rg] = rmv;
                if (llo == 0) rowmin[wn * 128 + rl] = rmv;
                const float thr = fminf(rmv, thrbuf[rl]) + MARGIN;
                #pragma unroll
                for (int fn = 0; fn < 8; ++fn) {
                    const bool p = d[fn] <= thr;
                    const unsigned long long mask = __ballot(p);
                    if (mask) {
                        if (p) {
                            const int col = (fn < 4) ? (cb0 + fn * 16) : (cb0 + 256 + (fn - 4) * 16);
                            const unsigned pos = wcount + mbcnt64(mask);
                            const unsigned v = ((unsigned)grow << 13) | (unsigned)col;
                            if (pos < SEG) wl[pos] = v;
                            else exact_rescore(z, cbp, z2g, e2g, grow, col, best);
                        }
                        wcount += (unsigned)__popcll(mask);
                    }
                }
            }
        }

        // per-wave flush to sharded list (one atomic per wave per tile)
        const unsigned n = wcount < SEG ? wcount : SEG;
        unsigned base = 0;
        if (lane == 0 && n) base = atomicAdd(&counters[wave * 16], n);
        base = (unsigned)__shfl((int)base, 0);
        for (unsigned i = lane; i < n; i += 64) {
            const unsigned v = wl[i];
            const unsigned slot = base + i;
            if (slot < C8) list[(size_t)wave * C8 + slot] = v;
            else exact_rescore(z, cbp, z2g, e2g, (int)(v >> 13), (int)(v & 8191u), best);
        }
    }
}

// ---------------- exact rescore of sharded candidate lists (wave per candidate) ----------------
__global__ __launch_bounds__(256) void k_rescore(
    const float* __restrict__ z, const float* __restrict__ cbp,
    const float* __restrict__ z2g, const float* __restrict__ e2g,
    const unsigned* __restrict__ list, const unsigned* __restrict__ counters, unsigned C8,
    unsigned long long* best)
{
    const unsigned wid = (blockIdx.x * blockDim.x + threadIdx.x) >> 6;
    const unsigned nw = (gridDim.x * blockDim.x) >> 6;
    const int lane = threadIdx.x & 63;
    #pragma unroll 1
    for (int s = 0; s < 8; ++s) {
        const unsigned n = min(counters[s * 16], C8);
        const unsigned* shard = list + (size_t)s * C8;
        for (unsigned i = wid; i < n; i += nw) {
            const unsigned v = shard[i];
            const unsigned row = v >> 13, col = v & 8191u;
            const float4 a = *reinterpret_cast<const float4*>(z + (size_t)row * DDIM + lane * 4);
            const float4 b = *reinterpret_cast<const float4*>(cbp + (size_t)col * DDIM + lane * 4);
            float sdot = fmaf(a.x, b.x, fmaf(a.y, b.y, fmaf(a.z, b.z, a.w * b.w)));
            #pragma unroll
            for (int off = 1; off < 64; off <<= 1) sdot += __shfl_xor(sdot, off);
            if (lane == 0) {
                const float de = z2g[row] + e2g[col] - 2.0f * sdot;
                const unsigned long long key =
                    ((unsigned long long)__float_as_uint(de) << 32) | col;
                atomicMin(&best[row], key);
            }
        }
    }
}

// ---------------- gather + z_st + loss + final scalars (ticket) ----------------
__global__ __launch_bounds__(1024) void k_gather(
    const float* __restrict__ z, const float* __restrict__ cbp,
    const unsigned long long* __restrict__ best,
    float* __restrict__ out, float* __restrict__ accum, unsigned* __restrict__ gctr)
{
    __shared__ float wsum[16];
    const int tid = threadIdx.x;
    const int row = blockIdx.x * 16 + (tid >> 6);
    const int lane = tid & 63;
    const unsigned k = (unsigned)(best[row] & 0xFFFFFFFFull);
    const float4 ze = *reinterpret_cast<const float4*>(z + (size_t)row * DDIM + lane * 4);
    const float4 cq = *reinterpret_cast<const float4*>(cbp + (size_t)k * DDIM + lane * 4);
    float4 zst;
    zst.x = ze.x + (cq.x - ze.x); zst.y = ze.y + (cq.y - ze.y);
    zst.z = ze.z + (cq.z - ze.z); zst.w = ze.w + (cq.w - ze.w);
    *reinterpret_cast<float4*>(out + (size_t)row * DDIM + lane * 4) = zst;
    const float dx = cq.x - ze.x, dy = cq.y - ze.y, dz = cq.z - ze.z, dw = cq.w - ze.w;
    float s = dx * dx + dy * dy + dz * dz + dw * dw;
    #pragma unroll
    for (int off = 32; off > 0; off >>= 1) s += __shfl_down(s, off);
    if (lane == 0) {
        wsum[tid >> 6] = s;
        out[(size_t)NROWS * DDIM + row] = (float)k;
    }
    __syncthreads();
    if (tid == 0) {
        float tot = 0.f;
        #pragma unroll
        for (int i = 0; i < 16; ++i) tot += wsum[i];
        atomicAdd(accum, tot);
        __threadfence();
        const unsigned t = atomicAdd(gctr, 1u);
        if (t == GATHER_BLOCKS - 1) {
            const float total = atomicAdd(accum, 0.0f);
            const float m = total / (float)(NROWS * DDIM);
            out[(size_t)NROWS * DDIM + NROWS + 0] = m;
            out[(size_t)NROWS * DDIM + NROWS + 1] = m;
        }
    }
}

extern "C" void kernel_launch(void* const* d_in, const int* in_sizes, int n_in,
                              void* d_out, int out_size, void* d_ws, size_t ws_size,
                              hipStream_t stream)
{
    const float* z  = (const float*)d_in[0];
    const float* cb = (const float*)d_in[1];
    float* out = (float*)d_out;

    // bf16 pre-tiled scratch lives in d_out's z_st region (12 MB of 16.8 MB),
    // consumed by k_screen/k_rescore and fully overwritten afterwards by k_gather.
    unsigned short* z_t  = (unsigned short*)d_out;                      // 8 MB
    unsigned short* cb_t = (unsigned short*)((char*)d_out + 8388608);   // 4 MB

    char* ws = (char*)d_ws;
    unsigned long long* best = (unsigned long long*)ws;   // 131072 B
    float* e2      = (float*)(ws + 131072);               // 32768 B
    float* z2      = (float*)(ws + 163840);               // 65536 B
    float* accum   = (float*)(ws + 229376);
    unsigned* gctr = (unsigned*)(ws + 229380);
    unsigned* counters = (unsigned*)(ws + 229440);        // 8 shard counters, 64B apart
    unsigned* list = (unsigned*)(ws + 230400);
    unsigned C8 = 0;
    if (ws_size > 230400 + 64) {
        size_t c = (ws_size - 230400) / 4 / 8;
        if (c > (1u << 20)) c = (1u << 20);
        C8 = (unsigned)c;
    }

    k_convert<<<384, 256, 0, stream>>>(z, z_t, cb, cb_t, z2, e2, best, accum, counters, gctr);
    k_screen<<<256, 512, 0, stream>>>(z, cb, z_t, cb_t, z2, e2, best, counters, list, C8);
    k_rescore<<<2048, 256, 0, stream>>>(z, cb, z2, e2, list, counters, C8, best);
    k_gather<<<GATHER_BLOCKS, 1024, 0, stream>>>(z, cb, best, out, accum, gctr);
}

// Round 11
// 294.807 us; speedup vs baseline: 1.5430x; 1.3476x over previous
//
#include <hip/hip_runtime.h>

#define NROWS 16384
#define KCODES 8192
#define DDIM 256
#define MARGIN 2.0f
#define SEG 128
#define NCT 16     // 512-col tiles (block sweeps all 8192 cols)
#define GATHER_BLOCKS (NROWS / 16)

typedef __attribute__((ext_vector_type(8))) short short8;
typedef __attribute__((ext_vector_type(4))) float f32x4;

// ---------------- helpers ----------------
__device__ inline unsigned short f2bf(float x) {
    unsigned u = __float_as_uint(x);
    return (unsigned short)((u + 0x7FFFu + ((u >> 16) & 1u)) >> 16);  // RNE
}

__device__ inline void gload16(const void* g, void* l) {
    __builtin_amdgcn_global_load_lds(
        (const __attribute__((address_space(1))) unsigned char*)g,
        (__attribute__((address_space(3))) unsigned char*)l, 16, 0, 0);
}

__device__ inline unsigned mbcnt64(unsigned long long m) {
    unsigned lo = __builtin_amdgcn_mbcnt_lo((unsigned)m, 0u);
    return __builtin_amdgcn_mbcnt_hi((unsigned)(m >> 32), lo);
}

__device__ inline void exact_rescore(const float* __restrict__ z, const float* __restrict__ cb,
                                     const float* __restrict__ z2g, const float* __restrict__ e2g,
                                     int grow, int gcol, unsigned long long* best) {
    const float4* av = reinterpret_cast<const float4*>(z + (size_t)grow * DDIM);
    const float4* bv = reinterpret_cast<const float4*>(cb + (size_t)gcol * DDIM);
    float dot = 0.f;
    #pragma unroll 8
    for (int j = 0; j < 64; ++j) {
        const float4 xa = av[j], xb = bv[j];
        dot = fmaf(xa.x, xb.x, fmaf(xa.y, xb.y, fmaf(xa.z, xb.z, fmaf(xa.w, xb.w, dot))));
    }
    const float de = z2g[grow] + e2g[gcol] - 2.0f * dot;
    const unsigned long long key =
        ((unsigned long long)__float_as_uint(de) << 32) | (unsigned)gcol;
    atomicMin(best + grow, key);
}

// ---------------- convert fp32 -> bf16 pre-tiled fragment layout + fused sumsq ----------------
// chunk (g, kb2): 1 KB, slot s: row g*16 + (s&15), k = kb2*32 + (s>>4)*8 .. +8
__global__ __launch_bounds__(256) void k_convert(
    const float* __restrict__ z, unsigned short* __restrict__ z_t,
    const float* __restrict__ cb, unsigned short* __restrict__ cb_t,
    float* __restrict__ z2, float* __restrict__ e2,
    unsigned long long* best, float* accum, unsigned* counters, unsigned* gctr)
{
    const int tid = threadIdx.x;
    const int bx = blockIdx.x;
    if (bx < 64) {
        const int gid = bx * 256 + tid;
        best[gid] = 0xFFFFFFFFFFFFFFFFull;
    }
    if (bx == 0) {
        if (tid < 16) counters[tid * 16] = 0u;
        if (tid == 0) { accum[0] = 0.0f; gctr[0] = 0u; }
    }
    const float* in;
    unsigned short* outt;
    float* sumsq;
    int g;
    if (bx < 256) { in = z;  outt = z_t;  sumsq = z2; g = bx * 4 + (tid >> 6); }
    else          { in = cb; outt = cb_t; sumsq = e2; g = (bx - 256) * 4 + (tid >> 6); }
    const int lane = tid & 63;
    const int row = g * 16 + (lane & 15);
    const int ko = (lane >> 4) * 8;
    float ss = 0.f;
    #pragma unroll
    for (int kb2 = 0; kb2 < 8; ++kb2) {
        const float4* src = reinterpret_cast<const float4*>(in + (size_t)row * DDIM + kb2 * 32 + ko);
        const float4 a = src[0], b = src[1];
        ss += a.x * a.x + a.y * a.y + a.z * a.z + a.w * a.w
            + b.x * b.x + b.y * b.y + b.z * b.z + b.w * b.w;
        short8 p;
        p[0] = (short)f2bf(a.x); p[1] = (short)f2bf(a.y); p[2] = (short)f2bf(a.z); p[3] = (short)f2bf(a.w);
        p[4] = (short)f2bf(b.x); p[5] = (short)f2bf(b.y); p[6] = (short)f2bf(b.z); p[7] = (short)f2bf(b.w);
        *reinterpret_cast<short8*>(outt + (((size_t)(g * 8 + kb2)) << 9) + lane * 8) = p;
    }
    ss += __shfl_xor(ss, 16);
    ss += __shfl_xor(ss, 32);
    if (lane < 16) sumsq[g * 16 + lane] = ss;
}

// ---------------- MFMA screen: 64 rows x ALL 8192 cols per block, two sweeps ----------------
// Sweep 1: per-thread register min of (e2 - 2 acc)  -> exact per-row global bf16 min.
// Sweep 2: recompute acc (deterministic), emit cols with value <= min + MARGIN.
// LDS: A 32K @0 | B dbuf 2x32K @32768 | rowmin[8][64] @98304 | thrbuf[64] @100352 | wl 16xSEG @100608
__global__ __launch_bounds__(1024, 4) void k_screen(
    const float* __restrict__ z, const float* __restrict__ cbp,
    const unsigned short* __restrict__ z_t, const unsigned short* __restrict__ cb_t,
    const float* __restrict__ z2g, const float* __restrict__ e2g,
    unsigned long long* __restrict__ best,
    unsigned* __restrict__ counters, unsigned* __restrict__ list, unsigned C16)
{
    __shared__ __align__(16) char smem[108800];
    char* ldsA = smem;
    char* ldsB = smem + 32768;
    float* rowmin = (float*)(smem + 98304);    // [8][64]
    float* thrbuf = (float*)(smem + 100352);   // [64]
    unsigned* wl_all = (unsigned*)(smem + 100608);

    const int tid = threadIdx.x;
    const int lane = tid & 63;
    const int wave = tid >> 6;     // 0..15
    const int wm = wave & 1;       // 32-row half
    const int wn = wave >> 1;      // 0..7 col-64 group
    const int lhi = lane >> 4;
    const int llo = lane & 15;

    const int rt = blockIdx.x;     // 256 blocks, 64-row bands
    const int row0 = rt * 64;

    // ---- prologue: stage A band (32 KB) + first B slice ----
    #pragma unroll
    for (int i = 0; i < 2; ++i) {
        const int c = wave * 2 + i;            // 0..31: gl = c>>3, kb2 = c&7
        gload16((const char*)z_t + (((size_t)((rt * 4 + (c >> 3)) * 8 + (c & 7))) << 10) + lane * 16,
                ldsA + c * 1024);
    }

    auto STAGE_B = [&](int b, int ct_, int kb2_) {
        #pragma unroll
        for (int i = 0; i < 2; ++i) {
            const int c = wave * 2 + i;        // col-16-group 0..31
            gload16((const char*)cb_t + (((size_t)((ct_ * 32 + c) * 8 + kb2_)) << 10) + lane * 16,
                    ldsB + b * 32768 + c * 1024);
        }
    };

    STAGE_B(0, 0, 0);
    __syncthreads();

    // ================= SWEEP 1: min only =================
    float rm[2][4];
    #pragma unroll
    for (int fm = 0; fm < 2; ++fm)
        #pragma unroll
        for (int rg = 0; rg < 4; ++rg) rm[fm][rg] = 3.0e38f;

    #pragma unroll 1
    for (int ci = 0; ci < NCT; ++ci) {
        f32x4 acc[2][4];
        #pragma unroll
        for (int i = 0; i < 2; ++i)
            #pragma unroll
            for (int j = 0; j < 4; ++j) { acc[i][j][0]=0.f; acc[i][j][1]=0.f; acc[i][j][2]=0.f; acc[i][j][3]=0.f; }

        #pragma unroll
        for (int kb2 = 0; kb2 < 8; ++kb2) {
            const int pb = kb2 & 1;
            if (kb2 < 7) STAGE_B(pb ^ 1, ci, kb2 + 1);
            else if (ci < NCT - 1) STAGE_B(pb ^ 1, ci + 1, 0);
            else STAGE_B(pb ^ 1, 0, 0);        // prefetch sweep-2 tile 0
            char* bufB = ldsB + pb * 32768;
            short8 bfr[4];
            #pragma unroll
            for (int fn = 0; fn < 4; ++fn)
                bfr[fn] = *reinterpret_cast<const short8*>(bufB + (wn * 4 + fn) * 1024 + lane * 16);
            #pragma unroll
            for (int fm = 0; fm < 2; ++fm) {
                const short8 af = *reinterpret_cast<const short8*>(
                    ldsA + (((wm * 2 + fm) * 8) + kb2) * 1024 + lane * 16);
                #pragma unroll
                for (int fn = 0; fn < 4; ++fn)
                    acc[fm][fn] = __builtin_amdgcn_mfma_f32_16x16x32_bf16(af, bfr[fn], acc[fm][fn], 0, 0, 0);
            }
            __syncthreads();
        }

        // epilogue: pure-register min update (no barriers, no LDS)
        float e2c[4];
        #pragma unroll
        for (int fn = 0; fn < 4; ++fn) e2c[fn] = e2g[ci * 512 + wn * 64 + fn * 16 + llo];
        #pragma unroll
        for (int fm = 0; fm < 2; ++fm) {
            #pragma unroll
            for (int rg = 0; rg < 4; ++rg) {
                float t0 = fmaf(-2.0f, acc[fm][0][rg], e2c[0]);
                float t1 = fmaf(-2.0f, acc[fm][1][rg], e2c[1]);
                float t2 = fmaf(-2.0f, acc[fm][2][rg], e2c[2]);
                float t3 = fmaf(-2.0f, acc[fm][3][rg], e2c[3]);
                rm[fm][rg] = fminf(rm[fm][rg], fminf(fminf(t0, t1), fminf(t2, t3)));
            }
        }
    }

    // ---- mid reduce: exact per-row global bf16 min -> thresholds ----
    #pragma unroll
    for (int fm = 0; fm < 2; ++fm) {
        #pragma unroll
        for (int rg = 0; rg < 4; ++rg) {
            float v = rm[fm][rg];
            #pragma unroll
            for (int off = 1; off < 16; off <<= 1) v = fminf(v, __shfl_xor(v, off));
            if (llo == 0) rowmin[wn * 64 + wm * 32 + fm * 16 + lhi * 4 + rg] = v;
        }
    }
    __syncthreads();
    if (tid < 64) {
        float a = rowmin[tid];
        #pragma unroll
        for (int q = 1; q < 8; ++q) a = fminf(a, rowmin[q * 64 + tid]);
        thrbuf[tid] = a + MARGIN;
    }
    __syncthreads();
    float thr2[2][4];
    #pragma unroll
    for (int fm = 0; fm < 2; ++fm)
        #pragma unroll
        for (int rg = 0; rg < 4; ++rg)
            thr2[fm][rg] = thrbuf[wm * 32 + fm * 16 + lhi * 4 + rg];

    // ================= SWEEP 2: emit only =================
    unsigned* wl = wl_all + wave * SEG;
    unsigned wcount = 0;

    #pragma unroll 1
    for (int ci = 0; ci < NCT; ++ci) {
        f32x4 acc[2][4];
        #pragma unroll
        for (int i = 0; i < 2; ++i)
            #pragma unroll
            for (int j = 0; j < 4; ++j) { acc[i][j][0]=0.f; acc[i][j][1]=0.f; acc[i][j][2]=0.f; acc[i][j][3]=0.f; }

        #pragma unroll
        for (int kb2 = 0; kb2 < 8; ++kb2) {
            const int pb = kb2 & 1;
            if (kb2 < 7) STAGE_B(pb ^ 1, ci, kb2 + 1);
            else if (ci < NCT - 1) STAGE_B(pb ^ 1, ci + 1, 0);
            char* bufB = ldsB + pb * 32768;
            short8 bfr[4];
            #pragma unroll
            for (int fn = 0; fn < 4; ++fn)
                bfr[fn] = *reinterpret_cast<const short8*>(bufB + (wn * 4 + fn) * 1024 + lane * 16);
            #pragma unroll
            for (int fm = 0; fm < 2; ++fm) {
                const short8 af = *reinterpret_cast<const short8*>(
                    ldsA + (((wm * 2 + fm) * 8) + kb2) * 1024 + lane * 16);
                #pragma unroll
                for (int fn = 0; fn < 4; ++fn)
                    acc[fm][fn] = __builtin_amdgcn_mfma_f32_16x16x32_bf16(af, bfr[fn], acc[fm][fn], 0, 0, 0);
            }
            __syncthreads();
        }

        // epilogue: compare vs precomputed thresholds; rare emission
        float e2c[4];
        #pragma unroll
        for (int fn = 0; fn < 4; ++fn) e2c[fn] = e2g[ci * 512 + wn * 64 + fn * 16 + llo];
        #pragma unroll
        for (int fm = 0; fm < 2; ++fm) {
            #pragma unroll
            for (int rg = 0; rg < 4; ++rg) {
                const float thr = thr2[fm][rg];
                float t[4];
                #pragma unroll
                for (int fn = 0; fn < 4; ++fn) t[fn] = fmaf(-2.0f, acc[fm][fn][rg], e2c[fn]);
                const bool hit = (t[0] <= thr) | (t[1] <= thr) | (t[2] <= thr) | (t[3] <= thr);
                if (__any(hit)) {
                    const int grow = row0 + wm * 32 + fm * 16 + lhi * 4 + rg;
                    #pragma unroll
                    for (int fn = 0; fn < 4; ++fn) {
                        const bool p = t[fn] <= thr;
                        const unsigned long long mask = __ballot(p);
                        if (mask) {
                            if (p) {
                                const int col = ci * 512 + wn * 64 + fn * 16 + llo;
                                const unsigned pos = wcount + mbcnt64(mask);
                                const unsigned v = ((unsigned)grow << 13) | (unsigned)col;
                                if (pos < SEG) wl[pos] = v;
                                else exact_rescore(z, cbp, z2g, e2g, grow, col, best);
                            }
                            wcount += (unsigned)__popcll(mask);
                        }
                    }
                }
            }
        }
    }

    // ---- final flush: one atomic per wave ----
    const unsigned n = wcount < SEG ? wcount : SEG;
    unsigned base = 0;
    if (lane == 0 && n) base = atomicAdd(&counters[wave * 16], n);
    base = (unsigned)__shfl((int)base, 0);
    for (unsigned i = lane; i < n; i += 64) {
        const unsigned v = wl[i];
        const unsigned slot = base + i;
        if (slot < C16) list[(size_t)wave * C16 + slot] = v;
        else exact_rescore(z, cbp, z2g, e2g, (int)(v >> 13), (int)(v & 8191u), best);
    }
}

// ---------------- exact rescore of sharded candidate lists (wave per candidate) ----------------
__global__ __launch_bounds__(256) void k_rescore(
    const float* __restrict__ z, const float* __restrict__ cbp,
    const float* __restrict__ z2g, const float* __restrict__ e2g,
    const unsigned* __restrict__ list, const unsigned* __restrict__ counters, unsigned C16,
    unsigned long long* best)
{
    const unsigned wid = (blockIdx.x * blockDim.x + threadIdx.x) >> 6;
    const unsigned nw = (gridDim.x * blockDim.x) >> 6;
    const int lane = threadIdx.x & 63;
    #pragma unroll 1
    for (int s = 0; s < 16; ++s) {
        const unsigned n = min(counters[s * 16], C16);
        const unsigned* shard = list + (size_t)s * C16;
        for (unsigned i = wid; i < n; i += nw) {
            const unsigned v = shard[i];
            const unsigned row = v >> 13, col = v & 8191u;
            const float4 a = *reinterpret_cast<const float4*>(z + (size_t)row * DDIM + lane * 4);
            const float4 b = *reinterpret_cast<const float4*>(cbp + (size_t)col * DDIM + lane * 4);
            float sdot = fmaf(a.x, b.x, fmaf(a.y, b.y, fmaf(a.z, b.z, a.w * b.w)));
            #pragma unroll
            for (int off = 1; off < 64; off <<= 1) sdot += __shfl_xor(sdot, off);
            if (lane == 0) {
                const float de = z2g[row] + e2g[col] - 2.0f * sdot;
                const unsigned long long key =
                    ((unsigned long long)__float_as_uint(de) << 32) | col;
                atomicMin(&best[row], key);
            }
        }
    }
}

// ---------------- gather + z_st + loss + final scalars (ticket) ----------------
__global__ __launch_bounds__(1024) void k_gather(
    const float* __restrict__ z, const float* __restrict__ cbp,
    const unsigned long long* __restrict__ best,
    float* __restrict__ out, float* __restrict__ accum, unsigned* __restrict__ gctr)
{
    __shared__ float wsum[16];
    const int tid = threadIdx.x;
    const int row = blockIdx.x * 16 + (tid >> 6);
    const int lane = tid & 63;
    const unsigned k = (unsigned)(best[row] & 0xFFFFFFFFull);
    const float4 ze = *reinterpret_cast<const float4*>(z + (size_t)row * DDIM + lane * 4);
    const float4 cq = *reinterpret_cast<const float4*>(cbp + (size_t)k * DDIM + lane * 4);
    float4 zst;
    zst.x = ze.x + (cq.x - ze.x); zst.y = ze.y + (cq.y - ze.y);
    zst.z = ze.z + (cq.z - ze.z); zst.w = ze.w + (cq.w - ze.w);
    *reinterpret_cast<float4*>(out + (size_t)row * DDIM + lane * 4) = zst;
    const float dx = cq.x - ze.x, dy = cq.y - ze.y, dz = cq.z - ze.z, dw = cq.w - ze.w;
    float s = dx * dx + dy * dy + dz * dz + dw * dw;
    #pragma unroll
    for (int off = 32; off > 0; off >>= 1) s += __shfl_down(s, off);
    if (lane == 0) {
        wsum[tid >> 6] = s;
        out[(size_t)NROWS * DDIM + row] = (float)k;
    }
    __syncthreads();
    if (tid == 0) {
        float tot = 0.f;
        #pragma unroll
        for (int i = 0; i < 16; ++i) tot += wsum[i];
        atomicAdd(accum, tot);
        __threadfence();
        const unsigned t = atomicAdd(gctr, 1u);
        if (t == GATHER_BLOCKS - 1) {
            const float total = atomicAdd(accum, 0.0f);
            const float m = total / (float)(NROWS * DDIM);
            out[(size_t)NROWS * DDIM + NROWS + 0] = m;
            out[(size_t)NROWS * DDIM + NROWS + 1] = m;
        }
    }
}

extern "C" void kernel_launch(void* const* d_in, const int* in_sizes, int n_in,
                              void* d_out, int out_size, void* d_ws, size_t ws_size,
                              hipStream_t stream)
{
    const float* z  = (const float*)d_in[0];
    const float* cb = (const float*)d_in[1];
    float* out = (float*)d_out;

    // bf16 pre-tiled scratch lives in d_out's z_st region (12 MB of 16.8 MB),
    // consumed by k_screen/k_rescore and fully overwritten afterwards by k_gather.
    unsigned short* z_t  = (unsigned short*)d_out;                      // 8 MB
    unsigned short* cb_t = (unsigned short*)((char*)d_out + 8388608);   // 4 MB

    char* ws = (char*)d_ws;
    unsigned long long* best = (unsigned long long*)ws;   // 131072 B
    float* e2      = (float*)(ws + 131072);               // 32768 B
    float* z2      = (float*)(ws + 163840);               // 65536 B
    float* accum   = (float*)(ws + 229376);
    unsigned* gctr = (unsigned*)(ws + 229380);
    unsigned* counters = (unsigned*)(ws + 229440);        // 16 shard counters, 64B apart
    unsigned* list = (unsigned*)(ws + 230464);
    unsigned C16 = 0;
    if (ws_size > 230464 + 64) {
        size_t c = (ws_size - 230464) / 4 / 16;
        if (c > (1u << 19)) c = (1u << 19);
        C16 = (unsigned)c;
    }

    k_convert<<<384, 256, 0, stream>>>(z, z_t, cb, cb_t, z2, e2, best, accum, counters, gctr);
    k_screen<<<256, 1024, 0, stream>>>(z, cb, z_t, cb_t, z2, e2, best, counters, list, C16);
    k_rescore<<<2048, 256, 0, stream>>>(z, cb, z2, e2, list, counters, C16, best);
    k_gather<<<GATHER_BLOCKS, 1024, 0, stream>>>(z, cb, best, out, accum, gctr);
}